// Round 8
// baseline (265.330 us; speedup 1.0000x reference)
//
#include <hip/hip_runtime.h>
#include <hip/hip_bf16.h>

#define D_FEAT 64
#define OVF_CAP 65536
#define NRMAX 32             // max ranges (4096 nodes each -> n <= 131072)
#define RS_EB 2048           // edges per k_rsplit block
#define NCH 16               // chunk-blocks per range in k_bsplit
#define CAPB 4096            // bucket segment capacity (= 128 nodes * 32 slots)
#define CSL 32               // slots per node

typedef unsigned int uint32;
typedef unsigned long long ull;

__device__ inline float blo(uint32 u) { return __uint_as_float(u << 16); }
__device__ inline float bhi(uint32 u) { return __uint_as_float(u & 0xffff0000u); }
__device__ inline float dinv(int d) { return (d > 0) ? rsqrtf((float)d) : 0.0f; }

// ---- pass 1: split edges into <=32 ranges (4096 nodes) by col>>12.
//      Ballot-compacted packed writes only: lines are block-private, written
//      once (rounds 4/5/6 showed scattered 4B writes run at ~1 line/edge
//      ~= 1 TB/s and cost ~100us; packed writes are traffic-bound).
__global__ __launch_bounds__(256) void k_rsplit(const int* __restrict__ row,
                                                const int* __restrict__ col,
                                                uint32* __restrict__ rseg,
                                                int* __restrict__ rcur,
                                                int* __restrict__ deg,
                                                int2* __restrict__ ovf,
                                                int* __restrict__ ovf_cnt,
                                                int E, int nr, int RCAP) {
    __shared__ int wcnt[4][NRMAX];
    __shared__ int wbase[4][NRMAX];
    const int wv = threadIdx.x >> 6;
    const int lane = threadIdx.x & 63;
    const ull mlt = ((ull)1 << lane) - 1;
    const int s = blockIdx.x * RS_EB;

    int cnt[NRMAX];
#pragma unroll
    for (int k = 0; k < NRMAX; ++k) cnt[k] = 0;
#pragma unroll
    for (int it = 0; it < RS_EB / 256; ++it) {
        int i = s + it * 256 + wv * 64 + lane;
        int b = 63;
        if (i < E) b = col[i] >> 12;
#pragma unroll
        for (int k = 0; k < NRMAX; ++k)
            cnt[k] += __popcll(__ballot(b == k));
    }
    if (lane == 0) {
#pragma unroll
        for (int k = 0; k < NRMAX; ++k) wcnt[wv][k] = cnt[k];
    }
    __syncthreads();
    if (threadIdx.x < NRMAX) {
        int k = threadIdx.x;
        int t0 = wcnt[0][k], t1 = wcnt[1][k], t2 = wcnt[2][k], t3 = wcnt[3][k];
        int tot = t0 + t1 + t2 + t3;
        int g = tot ? atomicAdd(&rcur[k], tot) : 0;
        wbase[0][k] = g;
        wbase[1][k] = g + t0;
        wbase[2][k] = g + t0 + t1;
        wbase[3][k] = g + t0 + t1 + t2;
    }
    __syncthreads();
    int run[NRMAX];
#pragma unroll
    for (int k = 0; k < NRMAX; ++k) run[k] = wbase[wv][k];
#pragma unroll
    for (int it = 0; it < RS_EB / 256; ++it) {
        int i = s + it * 256 + wv * 64 + lane;
        int b = 63, c = 0, r = 0;
        if (i < E) { c = col[i]; r = row[i]; b = c >> 12; }
#pragma unroll
        for (int k = 0; k < NRMAX; ++k) {
            ull m = __ballot(b == k);
            if (b == k) {
                int pos = run[k] + __popcll(m & mlt);
                if (pos < RCAP) {
                    rseg[(size_t)k * RCAP + pos] =
                        ((uint32)r << 12) | (uint32)(c & 4095);
                } else {                    // range overflow: exact via ovf
                    atomicAdd(&deg[c], 1);
                    int o = atomicAdd(ovf_cnt, 1);
                    if (o < OVF_CAP) ovf[o] = make_int2(r, c);
                }
            }
            run[k] += __popcll(m);
        }
    }
}

// ---- pass 2: per range, split into its 32 buckets of 128 nodes. Ballot-
//      packed writes into CAPB-padded bucket segments (4B entries r<<7|c&127).
__global__ __launch_bounds__(512) void k_bsplit(const uint32* __restrict__ rseg,
                                                const int* __restrict__ rcur,
                                                uint32* __restrict__ binned,
                                                int* __restrict__ cursor,
                                                int* __restrict__ deg,
                                                int2* __restrict__ ovf,
                                                int* __restrict__ ovf_cnt,
                                                int nr, int RCAP) {
    __shared__ int wcnt[8][32];
    __shared__ int wbase[8][32];
    const int rg = blockIdx.x & 31;
    if (rg >= nr) return;
    int len = rcur[rg];
    if (len > RCAP) len = RCAP;
    const uint32* sg = rseg + (size_t)rg * RCAP;
    const int wv = threadIdx.x >> 6;
    const int lane = threadIdx.x & 63;
    const ull mlt = ((ull)1 << lane) - 1;

    for (int c0 = (blockIdx.x >> 5) * 4096; c0 < len; c0 += NCH * 4096) {
        const int cend = (c0 + 4096 < len) ? c0 + 4096 : len;
        int cnt[32];
#pragma unroll
        for (int k = 0; k < 32; ++k) cnt[k] = 0;
#pragma unroll
        for (int it = 0; it < 8; ++it) {
            int i = c0 + it * 512 + wv * 64 + lane;
            int b = 63;
            if (i < cend) b = (int)((sg[i] >> 7) & 31);
#pragma unroll
            for (int k = 0; k < 32; ++k)
                cnt[k] += __popcll(__ballot(b == k));
        }
        if (lane == 0) {
#pragma unroll
            for (int k = 0; k < 32; ++k) wcnt[wv][k] = cnt[k];
        }
        __syncthreads();
        if (threadIdx.x < 32) {
            int k = threadIdx.x;
            int tot = 0, acc;
            int t[8];
#pragma unroll
            for (int w = 0; w < 8; ++w) { t[w] = wcnt[w][k]; tot += t[w]; }
            int g = tot ? atomicAdd(&cursor[(rg << 5) + k], tot) : 0;
            acc = g;
#pragma unroll
            for (int w = 0; w < 8; ++w) { wbase[w][k] = acc; acc += t[w]; }
        }
        __syncthreads();
        int run[32];
#pragma unroll
        for (int k = 0; k < 32; ++k) run[k] = wbase[wv][k];
#pragma unroll
        for (int it = 0; it < 8; ++it) {
            int i = c0 + it * 512 + wv * 64 + lane;
            int b = 63;
            uint32 v = 0;
            if (i < cend) { v = sg[i]; b = (int)((v >> 7) & 31); }
#pragma unroll
            for (int k = 0; k < 32; ++k) {
                ull m = __ballot(b == k);
                if (b == k) {
                    int pos = run[k] + __popcll(m & mlt);
                    int bk = (rg << 5) + k;
                    if (pos < CAPB) {
                        binned[(size_t)bk * CAPB + pos] =
                            ((v >> 12) << 7) | (v & 127u);
                    } else {                // bucket overflow: exact via ovf
                        int cf = (rg << 12) + (int)(v & 4095u);
                        atomicAdd(&deg[cf], 1);
                        int o = atomicAdd(ovf_cnt, 1);
                        if (o < OVF_CAP) ovf[o] = make_int2((int)(v >> 12), cf);
                    }
                }
                run[k] += __popcll(m);
            }
        }
        __syncthreads();                    // wcnt reuse next chunk
    }
}

// ---- pass 3: stage bucket segment to LDS, rank, write slots IN PLACE over
//      the dead segment (block-private window -> packed writes); emit
//      slot-count (into deg) + true-degree winv; fused bf16 cast of x
//      (cast lives here so rseg can alias xb -- disjoint lifetimes).
__global__ __launch_bounds__(512) void k_rank(const int* __restrict__ cursor,
                                              uint32* __restrict__ binned,
                                              int* __restrict__ deg,
                                              float* __restrict__ winv,
                                              const float2* __restrict__ x2,
                                              uint32* __restrict__ xb,
                                              int2* __restrict__ ovf,
                                              int* __restrict__ ovf_cnt,
                                              int n, int nbk, int nhalf) {
    __shared__ uint32 sh[CAPB];             // 16 KB
    __shared__ int cnt[128];
    const int bid = blockIdx.x;
    int tot = cursor[bid];
    if (tot > CAPB) tot = CAPB;
    uint32* win = binned + (size_t)bid * CAPB;
    for (int i = threadIdx.x; i < tot; i += 512) sh[i] = win[i];
    if (threadIdx.x < 128) cnt[threadIdx.x] = 0;
    __syncthreads();
    const int base = bid << 7;
    for (int i = threadIdx.x; i < tot; i += 512) {
        uint32 pk = sh[i];
        int cl = (int)(pk & 127);
        int r  = (int)(pk >> 7);
        int rk = atomicAdd(&cnt[cl], 1);
        if (rk < CSL) {
            win[(cl << 5) + rk] = (uint32)r; // == slots[node*32 + rk]
        } else {
            int o = atomicAdd(ovf_cnt, 1);
            if (o < OVF_CAP) ovf[o] = make_int2(r, base + cl);
        }
    }
    __syncthreads();
    if (threadIdx.x < 128) {
        int node = base + threadIdx.x;
        if (node < n) {
            int sc = cnt[threadIdx.x];
            int dtrue = deg[node] + sc;     // + split-overflow preseed
            winv[node] = dinv(dtrue);
            deg[node] = sc;                 // gather bound = slot count
        }
    }
    // fused bf16 cast, node-major linear
    for (int j = bid * 512 + threadIdx.x; j < nhalf; j += nbk * 512) {
        float2 v = x2[j];
        __hip_bfloat16 bx = __float2bfloat16(v.x);
        __hip_bfloat16 by = __float2bfloat16(v.y);
        uint32 ux = *reinterpret_cast<unsigned short*>(&bx);
        uint32 uy = *reinterpret_cast<unsigned short*>(&by);
        xb[j] = ux | (uy << 16);
    }
}

// ---- gather: one wave per node, 4 edges in parallel, 16-edge unroll ----
// (verified body: ~61 us, random-128B-fetch limited — do not touch)
__global__ void k_gather4d(const uint32* __restrict__ xb,
                           const float4* __restrict__ x4,
                           const int* __restrict__ deg,
                           const float* __restrict__ winv,
                           const int* __restrict__ slots,
                           const float* __restrict__ alpha_p,
                           const float* __restrict__ rs_p,
                           float4* __restrict__ out4, int n, int C) {
    int wid = (blockIdx.x * blockDim.x + threadIdx.x) >> 6;
    if (wid >= n) return;
    const int lane = threadIdx.x & 63;
    const int q = lane >> 4;
    const int l = lane & 15;
    int d = deg[wid];
    int e = (d < C) ? d : C;
    float4 xr = make_float4(0.f, 0.f, 0.f, 0.f);
    if (q == 0) xr = x4[(size_t)wid * 16 + l];
    const int* sl = slots + (size_t)wid * C;
    float ax = 0.f, ay = 0.f, az = 0.f, aw = 0.f;
    int k = 0;
    for (; k + 16 <= e; k += 16) {
        int s0 = sl[k + q];
        int s1 = sl[k + 4 + q];
        int s2 = sl[k + 8 + q];
        int s3 = sl[k + 12 + q];
        float w0 = winv[s0], w1 = winv[s1], w2 = winv[s2], w3 = winv[s3];
        uint2 p0 = ((const uint2*)(xb + (size_t)s0 * 32))[l];
        uint2 p1 = ((const uint2*)(xb + (size_t)s1 * 32))[l];
        uint2 p2 = ((const uint2*)(xb + (size_t)s2 * 32))[l];
        uint2 p3 = ((const uint2*)(xb + (size_t)s3 * 32))[l];
        ax = fmaf(w0, blo(p0.x), ax); ay = fmaf(w0, bhi(p0.x), ay);
        az = fmaf(w0, blo(p0.y), az); aw = fmaf(w0, bhi(p0.y), aw);
        ax = fmaf(w1, blo(p1.x), ax); ay = fmaf(w1, bhi(p1.x), ay);
        az = fmaf(w1, blo(p1.y), az); aw = fmaf(w1, bhi(p1.y), aw);
        ax = fmaf(w2, blo(p2.x), ax); ay = fmaf(w2, bhi(p2.x), ay);
        az = fmaf(w2, blo(p2.y), az); aw = fmaf(w2, bhi(p2.y), aw);
        ax = fmaf(w3, blo(p3.x), ax); ay = fmaf(w3, bhi(p3.x), ay);
        az = fmaf(w3, blo(p3.y), az); aw = fmaf(w3, bhi(p3.y), aw);
    }
    for (; k < e; k += 4) {
        int kk = k + q;
        if (kk < e) {
            int s0 = sl[kk];
            float w0 = winv[s0];
            uint2 p0 = ((const uint2*)(xb + (size_t)s0 * 32))[l];
            ax = fmaf(w0, blo(p0.x), ax); ay = fmaf(w0, bhi(p0.x), ay);
            az = fmaf(w0, blo(p0.y), az); aw = fmaf(w0, bhi(p0.y), aw);
        }
    }
    ax += __shfl_down(ax, 32, 64); ay += __shfl_down(ay, 32, 64);
    az += __shfl_down(az, 32, 64); aw += __shfl_down(aw, 32, 64);
    ax += __shfl_down(ax, 16, 64); ay += __shfl_down(ay, 16, 64);
    az += __shfl_down(az, 16, 64); aw += __shfl_down(aw, 16, 64);
    if (q == 0) {
        float adw = (*alpha_p) * winv[wid];
        float rs  = *rs_p;
        float4 o;
        o.x = fmaf(adw, ax, rs * xr.x);
        o.y = fmaf(adw, ay, rs * xr.y);
        o.z = fmaf(adw, az, rs * xr.z);
        o.w = fmaf(adw, aw, rs * xr.w);
        out4[(size_t)wid * 16 + l] = o;
    }
}

// ---- overflow fix-up (split overflow or deg>CSL; empty for uniform input) ----
__global__ void k_ovf(const int2* __restrict__ ovf, const int* __restrict__ cnt_p,
                      const float* __restrict__ x, const float* __restrict__ winv,
                      const float* __restrict__ alpha_p, float* __restrict__ out) {
    int cnt = *cnt_p;
    if (cnt > OVF_CAP) cnt = OVF_CAP;
    if (cnt <= 0) return;
    float a = *alpha_p;
    long long total = (long long)cnt * 64;
    long long stride = (long long)gridDim.x * blockDim.x;
    for (long long idx = blockIdx.x * (long long)blockDim.x + threadIdx.x;
         idx < total; idx += stride) {
        int e = (int)(idx >> 6);
        int f = (int)(idx & 63);
        int2 rc = ovf[e];
        float w = a * winv[rc.x] * winv[rc.y];
        atomicAdd(&out[(size_t)rc.y * D_FEAT + f], w * x[(size_t)rc.x * D_FEAT + f]);
    }
}

// ---- winv table for the fallback path ----
__global__ void k_winv(const int* __restrict__ deg, float* __restrict__ winv, int n) {
    int i = blockIdx.x * blockDim.x + threadIdx.x;
    if (i < n) winv[i] = dinv(deg[i]);
}

// ================= fallback: direct padded-CSR build (round 4) ===============
__global__ __launch_bounds__(256) void k_prep(const float2* __restrict__ x2,
                                              uint32* __restrict__ xb,
                                              const int* __restrict__ row,
                                              const int* __restrict__ col,
                                              int* __restrict__ deg,
                                              int* __restrict__ slots,
                                              int2* __restrict__ ovf,
                                              int* __restrict__ ovf_cnt,
                                              int nhalf, int E, int C) {
    const int t = blockIdx.x * blockDim.x + threadIdx.x;
    if (t < E) {
        int c = col[t];
        int r = row[t];
        int rk = atomicAdd(&deg[c], 1);
        if (rk < C) {
            slots[(size_t)c * C + rk] = r;
        } else {
            int o = atomicAdd(ovf_cnt, 1);
            if (o < OVF_CAP) ovf[o] = make_int2(r, c);
        }
    }
    const int stride = gridDim.x * blockDim.x;
    for (int j = t; j < nhalf; j += stride) {
        float2 v = x2[j];
        __hip_bfloat16 bx = __float2bfloat16(v.x);
        __hip_bfloat16 by = __float2bfloat16(v.y);
        uint32 ux = *reinterpret_cast<unsigned short*>(&bx);
        uint32 uy = *reinterpret_cast<unsigned short*>(&by);
        xb[j] = ux | (uy << 16);
    }
}

static inline char* align_up(char* p, size_t a) {
    return (char*)(((uintptr_t)p + (a - 1)) & ~(uintptr_t)(a - 1));
}

extern "C" void kernel_launch(void* const* d_in, const int* in_sizes, int n_in,
                              void* d_out, int out_size, void* d_ws, size_t ws_size,
                              hipStream_t stream) {
    const float* x         = (const float*)d_in[0];
    const float* alpha     = (const float*)d_in[1];
    const float* res_scale = (const float*)d_in[2];
    const int*   ei        = (const int*)d_in[3];

    const int n = in_sizes[0] / D_FEAT;      // 100000
    const int E = in_sizes[3] / 2;           // 1600000
    const int* row = ei;                     // sources
    const int* col = ei + E;                 // targets

    float* out = (float*)d_out;
    const int nhalf = n * (D_FEAT / 2);
    const int nr  = (n + 4095) >> 12;        // ranges (25)
    const int nbk = nr << 5;                 // buckets (800)

    // ---------- two-level packed radix split + in-place rank + gather ----------
    {
        char* p = (char*)d_ws;
        int*    deg     = (int*)p;            p += (size_t)n * 4;
        int*    cursor  = (int*)p;            p += (size_t)(NRMAX * 32) * 4;
        int*    rcur    = (int*)p;            p += NRMAX * 4;
        int*    ovf_cnt = (int*)p;            p += 4;
        float*  winv    = (float*)p;          p += (size_t)n * 4;
        int2*   ovf     = (int2*)p;           p += (size_t)OVF_CAP * 8;
        p = align_up(p, 16);
        uint32* xb      = (uint32*)p;         p += (size_t)n * 128;   // aliases rseg
        p = align_up(p, 16);
        uint32* binned  = (uint32*)p;         p += (size_t)nbk * CAPB * 4;
        const size_t need = (size_t)(p - (char*)d_ws);

        uint32* rseg = xb;                    // disjoint lifetimes (cast in k_rank)
        const int RCAP = (int)(((size_t)n * 128 / 4) / nr);  // entries per range

        const bool ok = (nr <= NRMAX) && (n <= (1 << 17)) &&
                        (RCAP >= E / nr + 8192) && (need <= ws_size);
        if (ok) {
            // zero deg + cursor + rcur + ovf_cnt (contiguous)
            hipMemsetAsync(deg, 0, (size_t)(n + NRMAX * 32 + NRMAX + 1) * 4, stream);
            const int B1 = (E + RS_EB - 1) / RS_EB;
            k_rsplit<<<B1, 256, 0, stream>>>(row, col, rseg, rcur, deg,
                                             ovf, ovf_cnt, E, nr, RCAP);
            k_bsplit<<<32 * NCH, 512, 0, stream>>>(rseg, rcur, binned, cursor,
                                                   deg, ovf, ovf_cnt, nr, RCAP);
            k_rank<<<nbk, 512, 0, stream>>>(cursor, binned, deg, winv,
                                            (const float2*)x, xb, ovf, ovf_cnt,
                                            n, nbk, nhalf);
            const long long tt = (long long)n * D_FEAT;
            const int blocks = (int)((tt + 255) / 256);
            // slots == binned: node window stride CSL=32 (bucket*4096 + cl*32)
            k_gather4d<<<blocks, 256, 0, stream>>>(xb, (const float4*)x, deg, winv,
                                                   (const int*)binned, alpha,
                                                   res_scale, (float4*)out, n, CSL);
            k_ovf<<<64, 256, 0, stream>>>(ovf, ovf_cnt, x, winv, alpha, out);
            return;
        }
    }

    // ---------- fallback: direct scatter build (round-4 path) ----------
    {
        char* q = (char*)d_ws;
        int*    degf    = (int*)q;            q += (size_t)n * 4;
        int*    ovf_cf  = (int*)q;            q += 4;
        float*  winvf   = (float*)q;          q += (size_t)n * 4;
        int2*   ovff    = (int2*)q;           q += (size_t)OVF_CAP * 8;
        q = align_up(q, 16);
        uint32* xbf     = (uint32*)q;         q += (size_t)n * 128;
        int*    slotsf  = (int*)q;
        const size_t fxd = (size_t)(q - (char*)d_ws);
        int Cf = 0;
        if (ws_size > fxd) {
            size_t c_avail = (ws_size - fxd) / ((size_t)n * 4);
            Cf = (c_avail > 32) ? 32 : (int)c_avail;
        }
        if (Cf < 1) return;
        hipMemsetAsync(degf, 0, (size_t)n * 4 + 4, stream);
        k_prep<<<(E + 255) / 256, 256, 0, stream>>>(
            (const float2*)x, xbf, row, col, degf, slotsf, ovff, ovf_cf,
            nhalf, E, Cf);
        k_winv<<<(n + 255) / 256, 256, 0, stream>>>(degf, winvf, n);
        const long long tt = (long long)n * D_FEAT;
        const int blocks = (int)((tt + 255) / 256);
        k_gather4d<<<blocks, 256, 0, stream>>>(xbf, (const float4*)x, degf, winvf,
                                               slotsf, alpha, res_scale,
                                               (float4*)out, n, Cf);
        k_ovf<<<64, 256, 0, stream>>>(ovff, ovf_cf, x, winvf, alpha, out);
    }
}

// Round 9
// 222.995 us; speedup vs baseline: 1.1898x; 1.1898x over previous
//
#include <hip/hip_runtime.h>
#include <hip/hip_bf16.h>
#include <hip/hip_cooperative_groups.h>

namespace cg = cooperative_groups;

#define D_FEAT 64
#define OVF_CAP 65536
#define NBMAX 1024           // max buckets (128 nodes each -> n <= 131072)
#define CAPB 4096            // bucket segment capacity
#define CSL 32               // slots per node

typedef unsigned int uint32;

__device__ inline float blo(uint32 u) { return __uint_as_float(u << 16); }
__device__ inline float bhi(uint32 u) { return __uint_as_float(u & 0xffff0000u); }
__device__ inline float dinv(int d) { return (d > 0) ? rsqrtf((float)d) : 0.0f; }

// ================= ONE cooperative kernel: zero -> bin -> rank -> gather ====
// Lesson ledger baked in:
//  - r4/r5: never emit per-edge scattered 4B global writes (1 line/edge).
//  - r8: never ballot-compact over 32 bins (VALU-bound).
//  - r2/r3: never run the build at <10 waves/CU (latency-bound).
//  - r7: coop works, but EVERY block must bin (256/782 starved the machine).
//  - r4 ledger: 5 dispatches cost ~50us fixed -> fuse to 1.
__global__ __launch_bounds__(512, 8) void k_coop(
    const int* __restrict__ row, const int* __restrict__ col,
    const float2* __restrict__ x2, uint32* __restrict__ xb,
    int* __restrict__ deg, float* __restrict__ winv,
    int* __restrict__ cursor, uint32* __restrict__ binned,
    int2* __restrict__ ovf, int* __restrict__ ovf_cnt,
    const float* __restrict__ alpha_p, const float* __restrict__ rs_p,
    const float4* __restrict__ x4, float4* __restrict__ out4,
    float* __restrict__ outf,
    int n, int E, int nb, int EB2, int nhalf)
{
    __shared__ int   slots[128 * CSL];     // 16 KB; aliased as hist in bin phase
    __shared__ int   cnt[128];
    __shared__ float winvl[128];
    const int bid = blockIdx.x;
    const int tid = threadIdx.x;
    cg::grid_group grid = cg::this_grid();

    // ---------------- phase 0: zero workspace ----------------
    for (int i = bid * 512 + tid; i < n;  i += nb * 512) deg[i] = 0;
    for (int i = bid * 512 + tid; i < nb; i += nb * 512) cursor[i] = 0;
    if (bid == 0 && tid == 0) *ovf_cnt = 0;
    grid.sync();

    // ---------------- phase 1: bin (ALL blocks) + cast ----------------
    {
        int* h = slots;                    // nb <= 1024 ints
        for (int i = tid; i < nb; i += 512) h[i] = 0;
        __syncthreads();
        const int s = bid * EB2;
        const int e = (s + EB2 < E) ? s + EB2 : E;
        for (int i = s + tid; i < e; i += 512)
            atomicAdd(&h[col[i] >> 7], 1);
        __syncthreads();
        // reservation, staggered by bid to spread per-cursor contention
        const int off = bid & 255;         // < nb always (nb >= 256 when ok)
        for (int k0 = tid; k0 < nb; k0 += 512) {
            int k = k0 + off; if (k >= nb) k -= nb;
            int c = h[k];
            if (c) h[k] = atomicAdd(&cursor[k], c);
        }
        __syncthreads();
        for (int i = s + tid; i < e; i += 512) {
            int c = col[i];
            uint32 r = (uint32)row[i];
            int b = c >> 7;
            int pos = atomicAdd(&h[b], 1);
            if (pos < CAPB) {
                binned[(size_t)b * CAPB + pos] = (r << 7) | (uint32)(c & 127);
            } else {                       // segment full: preseed deg, fix later
                atomicAdd(&deg[c], 1);
                int o = atomicAdd(ovf_cnt, 1);
                if (o < OVF_CAP) ovf[o] = make_int2((int)r, c);
            }
        }
    }
    // fused bf16 cast (overlaps other blocks' binning)
    for (int j = bid * 512 + tid; j < nhalf; j += nb * 512) {
        float2 v = x2[j];
        __hip_bfloat16 bx = __float2bfloat16(v.x);
        __hip_bfloat16 by = __float2bfloat16(v.y);
        uint32 ux = *reinterpret_cast<unsigned short*>(&bx);
        uint32 uy = *reinterpret_cast<unsigned short*>(&by);
        xb[j] = ux | (uy << 16);
    }
    grid.sync();

    // ---------------- phase 2: rank into LDS slots + deg/winv ----------------
    if (tid < 128) cnt[tid] = 0;
    __syncthreads();
    const int base = bid << 7;
    int tot = cursor[bid];
    if (tot > CAPB) tot = CAPB;
    const uint32* seg = binned + (size_t)bid * CAPB;
    for (int i = tid; i < tot; i += 512) {
        uint32 pk = seg[i];
        int cl = (int)(pk & 127);
        int r  = (int)(pk >> 7);
        int rk = atomicAdd(&cnt[cl], 1);              // LDS atomic
        if (rk < CSL) {
            slots[(cl << 5) + rk] = r;
        } else {
            int o = atomicAdd(ovf_cnt, 1);
            if (o < OVF_CAP) ovf[o] = make_int2(r, base + cl);
        }
    }
    __syncthreads();
    if (tid < 128) {
        int node = base + tid;
        if (node < n) {
            int d = cnt[tid] + deg[node];             // + CAPB-overflow preseed
            float w = dinv(d);
            winv[node] = w;
            winvl[tid] = w;
        } else {
            winvl[tid] = 0.f;
        }
    }
    grid.sync();

    // ---------------- phase 3: gather (verified 4-edge-parallel body) -------
    {
        const int wv   = tid >> 6;                    // wave 0..7
        const int lane = tid & 63;
        const int q = lane >> 4;                      // edge group 0..3
        const int l = lane & 15;                      // float4 index in row
        const float alpha = *alpha_p;
        const float rs = *rs_p;
        for (int nl = (wv << 4); nl < (wv << 4) + 16; ++nl) {   // 16 nodes/wave
            int node = base + nl;
            if (node >= n) break;                     // wave-uniform
            int e = cnt[nl];
            if (e > CSL) e = CSL;
            float4 xr = make_float4(0.f, 0.f, 0.f, 0.f);
            if (q == 0) xr = x4[(size_t)node * 16 + l];
            const int* sl = &slots[nl << 5];
            float ax = 0.f, ay = 0.f, az = 0.f, aw = 0.f;
            int k = 0;
            for (; k + 16 <= e; k += 16) {
                int s0 = sl[k + q];
                int s1 = sl[k + 4 + q];
                int s2 = sl[k + 8 + q];
                int s3 = sl[k + 12 + q];
                float w0 = winv[s0], w1 = winv[s1], w2 = winv[s2], w3 = winv[s3];
                uint2 p0 = ((const uint2*)(xb + (size_t)s0 * 32))[l];
                uint2 p1 = ((const uint2*)(xb + (size_t)s1 * 32))[l];
                uint2 p2 = ((const uint2*)(xb + (size_t)s2 * 32))[l];
                uint2 p3 = ((const uint2*)(xb + (size_t)s3 * 32))[l];
                ax = fmaf(w0, blo(p0.x), ax); ay = fmaf(w0, bhi(p0.x), ay);
                az = fmaf(w0, blo(p0.y), az); aw = fmaf(w0, bhi(p0.y), aw);
                ax = fmaf(w1, blo(p1.x), ax); ay = fmaf(w1, bhi(p1.x), ay);
                az = fmaf(w1, blo(p1.y), az); aw = fmaf(w1, bhi(p1.y), aw);
                ax = fmaf(w2, blo(p2.x), ax); ay = fmaf(w2, bhi(p2.x), ay);
                az = fmaf(w2, blo(p2.y), az); aw = fmaf(w2, bhi(p2.y), aw);
                ax = fmaf(w3, blo(p3.x), ax); ay = fmaf(w3, bhi(p3.x), ay);
                az = fmaf(w3, blo(p3.y), az); aw = fmaf(w3, bhi(p3.y), aw);
            }
            for (; k < e; k += 4) {
                int kk = k + q;
                if (kk < e) {
                    int s0 = sl[kk];
                    float w0 = winv[s0];
                    uint2 p0 = ((const uint2*)(xb + (size_t)s0 * 32))[l];
                    ax = fmaf(w0, blo(p0.x), ax); ay = fmaf(w0, bhi(p0.x), ay);
                    az = fmaf(w0, blo(p0.y), az); aw = fmaf(w0, bhi(p0.y), aw);
                }
            }
            ax += __shfl_down(ax, 32, 64); ay += __shfl_down(ay, 32, 64);
            az += __shfl_down(az, 32, 64); aw += __shfl_down(aw, 32, 64);
            ax += __shfl_down(ax, 16, 64); ay += __shfl_down(ay, 16, 64);
            az += __shfl_down(az, 16, 64); aw += __shfl_down(aw, 16, 64);
            if (q == 0) {
                float adw = alpha * winvl[nl];
                float4 o;
                o.x = fmaf(adw, ax, rs * xr.x);
                o.y = fmaf(adw, ay, rs * xr.y);
                o.z = fmaf(adw, az, rs * xr.z);
                o.w = fmaf(adw, aw, rs * xr.w);
                out4[(size_t)node * 16 + l] = o;
            }
        }
    }

    // ---------------- phase 4: overflow fix-up (normally empty) -------------
    grid.sync();
    int oc = *ovf_cnt;
    if (oc > OVF_CAP) oc = OVF_CAP;
    if (oc > 0) {
        const float* xf = (const float*)x2;
        float a = *alpha_p;
        long long total = (long long)oc * 64;
        long long stride = (long long)nb * 512;
        for (long long idx = bid * 512LL + tid; idx < total; idx += stride) {
            int e = (int)(idx >> 6);
            int f = (int)(idx & 63);
            int2 rc = ovf[e];
            float w = a * winv[rc.x] * winv[rc.y];
            atomicAdd(&outf[(size_t)rc.y * D_FEAT + f],
                      w * xf[(size_t)rc.x * D_FEAT + f]);
        }
    }
}

// ---- standalone overflow fix-up for the fallback path ----
__global__ void k_ovf(const int2* __restrict__ ovf, const int* __restrict__ cnt_p,
                      const float* __restrict__ x, const float* __restrict__ winv,
                      const float* __restrict__ alpha_p, float* __restrict__ out) {
    int cnt = *cnt_p;
    if (cnt > OVF_CAP) cnt = OVF_CAP;
    if (cnt <= 0) return;
    float a = *alpha_p;
    long long total = (long long)cnt * 64;
    long long stride = (long long)gridDim.x * blockDim.x;
    for (long long idx = blockIdx.x * (long long)blockDim.x + threadIdx.x;
         idx < total; idx += stride) {
        int e = (int)(idx >> 6);
        int f = (int)(idx & 63);
        int2 rc = ovf[e];
        float w = a * winv[rc.x] * winv[rc.y];
        atomicAdd(&out[(size_t)rc.y * D_FEAT + f], w * x[(size_t)rc.x * D_FEAT + f]);
    }
}

// ---- winv table for the fallback path ----
__global__ void k_winv(const int* __restrict__ deg, float* __restrict__ winv, int n) {
    int i = blockIdx.x * blockDim.x + threadIdx.x;
    if (i < n) winv[i] = dinv(deg[i]);
}

// ================= fallback: direct padded-CSR build (round 4) ===============
__global__ __launch_bounds__(256) void k_prep(const float2* __restrict__ x2,
                                              uint32* __restrict__ xb,
                                              const int* __restrict__ row,
                                              const int* __restrict__ col,
                                              int* __restrict__ deg,
                                              int* __restrict__ slots,
                                              int2* __restrict__ ovf,
                                              int* __restrict__ ovf_cnt,
                                              int nhalf, int E, int C) {
    const int t = blockIdx.x * blockDim.x + threadIdx.x;
    if (t < E) {
        int c = col[t];
        int r = row[t];
        int rk = atomicAdd(&deg[c], 1);
        if (rk < C) {
            slots[(size_t)c * C + rk] = r;
        } else {
            int o = atomicAdd(ovf_cnt, 1);
            if (o < OVF_CAP) ovf[o] = make_int2(r, c);
        }
    }
    const int stride = gridDim.x * blockDim.x;
    for (int j = t; j < nhalf; j += stride) {
        float2 v = x2[j];
        __hip_bfloat16 bx = __float2bfloat16(v.x);
        __hip_bfloat16 by = __float2bfloat16(v.y);
        uint32 ux = *reinterpret_cast<unsigned short*>(&bx);
        uint32 uy = *reinterpret_cast<unsigned short*>(&by);
        xb[j] = ux | (uy << 16);
    }
}

// fallback gather (global slots; verified round-0 body)
__global__ void k_gather4d(const uint32* __restrict__ xb,
                           const float4* __restrict__ x4,
                           const int* __restrict__ deg,
                           const float* __restrict__ winv,
                           const int* __restrict__ slots,
                           const float* __restrict__ alpha_p,
                           const float* __restrict__ rs_p,
                           float4* __restrict__ out4, int n, int C) {
    int wid = (blockIdx.x * blockDim.x + threadIdx.x) >> 6;
    if (wid >= n) return;
    const int lane = threadIdx.x & 63;
    const int q = lane >> 4;
    const int l = lane & 15;
    int d = deg[wid];
    int e = (d < C) ? d : C;
    float4 xr = make_float4(0.f, 0.f, 0.f, 0.f);
    if (q == 0) xr = x4[(size_t)wid * 16 + l];
    const int* sl = slots + (size_t)wid * C;
    float ax = 0.f, ay = 0.f, az = 0.f, aw = 0.f;
    int k = 0;
    for (; k + 16 <= e; k += 16) {
        int s0 = sl[k + q];
        int s1 = sl[k + 4 + q];
        int s2 = sl[k + 8 + q];
        int s3 = sl[k + 12 + q];
        float w0 = winv[s0], w1 = winv[s1], w2 = winv[s2], w3 = winv[s3];
        uint2 p0 = ((const uint2*)(xb + (size_t)s0 * 32))[l];
        uint2 p1 = ((const uint2*)(xb + (size_t)s1 * 32))[l];
        uint2 p2 = ((const uint2*)(xb + (size_t)s2 * 32))[l];
        uint2 p3 = ((const uint2*)(xb + (size_t)s3 * 32))[l];
        ax = fmaf(w0, blo(p0.x), ax); ay = fmaf(w0, bhi(p0.x), ay);
        az = fmaf(w0, blo(p0.y), az); aw = fmaf(w0, bhi(p0.y), aw);
        ax = fmaf(w1, blo(p1.x), ax); ay = fmaf(w1, bhi(p1.x), ay);
        az = fmaf(w1, blo(p1.y), az); aw = fmaf(w1, bhi(p1.y), aw);
        ax = fmaf(w2, blo(p2.x), ax); ay = fmaf(w2, bhi(p2.x), ay);
        az = fmaf(w2, blo(p2.y), az); aw = fmaf(w2, bhi(p2.y), aw);
        ax = fmaf(w3, blo(p3.x), ax); ay = fmaf(w3, bhi(p3.x), ay);
        az = fmaf(w3, blo(p3.y), az); aw = fmaf(w3, bhi(p3.y), aw);
    }
    for (; k < e; k += 4) {
        int kk = k + q;
        if (kk < e) {
            int s0 = sl[kk];
            float w0 = winv[s0];
            uint2 p0 = ((const uint2*)(xb + (size_t)s0 * 32))[l];
            ax = fmaf(w0, blo(p0.x), ax); ay = fmaf(w0, bhi(p0.x), ay);
            az = fmaf(w0, blo(p0.y), az); aw = fmaf(w0, bhi(p0.y), aw);
        }
    }
    ax += __shfl_down(ax, 32, 64); ay += __shfl_down(ay, 32, 64);
    az += __shfl_down(az, 32, 64); aw += __shfl_down(aw, 32, 64);
    ax += __shfl_down(ax, 16, 64); ay += __shfl_down(ay, 16, 64);
    az += __shfl_down(az, 16, 64); aw += __shfl_down(aw, 16, 64);
    if (q == 0) {
        float adw = (*alpha_p) * winv[wid];
        float rs  = *rs_p;
        float4 o;
        o.x = fmaf(adw, ax, rs * xr.x);
        o.y = fmaf(adw, ay, rs * xr.y);
        o.z = fmaf(adw, az, rs * xr.z);
        o.w = fmaf(adw, aw, rs * xr.w);
        out4[(size_t)wid * 16 + l] = o;
    }
}

static inline char* align_up(char* p, size_t a) {
    return (char*)(((uintptr_t)p + (a - 1)) & ~(uintptr_t)(a - 1));
}

extern "C" void kernel_launch(void* const* d_in, const int* in_sizes, int n_in,
                              void* d_out, int out_size, void* d_ws, size_t ws_size,
                              hipStream_t stream) {
    const float* x         = (const float*)d_in[0];
    const float* alpha     = (const float*)d_in[1];
    const float* res_scale = (const float*)d_in[2];
    const int*   ei        = (const int*)d_in[3];

    const int n = in_sizes[0] / D_FEAT;      // 100000
    const int E = in_sizes[3] / 2;           // 1600000
    const int* row = ei;                     // sources
    const int* col = ei + E;                 // targets

    float* out = (float*)d_out;
    const int nhalf = n * (D_FEAT / 2);
    const int nb = (n + 127) >> 7;           // 128-node buckets (782)
    const int EB2 = (E + nb - 1) / nb;       // edges per block in bin phase

    // ---------- one cooperative dispatch ----------
    {
        char* p = (char*)d_ws;
        int*    deg     = (int*)p;            p += (size_t)n * 4;
        int*    cursor  = (int*)p;            p += (size_t)nb * 4;
        int*    ovf_cnt = (int*)p;            p += 4;
        float*  winv    = (float*)p;          p += (size_t)n * 4;
        int2*   ovf     = (int2*)p;           p += (size_t)OVF_CAP * 8;
        p = align_up(p, 16);
        uint32* xb      = (uint32*)p;         p += (size_t)n * 128;
        p = align_up(p, 16);
        uint32* binned  = (uint32*)p;         p += (size_t)nb * CAPB * 4;
        const size_t need = (size_t)(p - (char*)d_ws);

        static int coop_cap = -1;
        if (coop_cap < 0) {
            int perCU = 0, nCU = 0, dev = 0;
            hipGetDevice(&dev);
            if (hipOccupancyMaxActiveBlocksPerMultiprocessor(&perCU, k_coop,
                                                             512, 0) != hipSuccess)
                perCU = 0;
            if (hipDeviceGetAttribute(&nCU, hipDeviceAttributeMultiprocessorCount,
                                      dev) != hipSuccess)
                nCU = 0;
            coop_cap = perCU * nCU;
        }

        const bool ok = (need <= ws_size) && (nb >= 256) && (nb <= NBMAX) &&
                        (n <= (NBMAX << 7)) && (nb <= coop_cap);
        if (ok) {
            const int*    row_a = row;      const int*   col_a = col;
            const float2* x2_a  = (const float2*)x;
            uint32*       xb_a  = xb;       int*         deg_a = deg;
            float*        wv_a  = winv;     int*         cur_a = cursor;
            uint32*       bin_a = binned;   int2*        ovf_a = ovf;
            int*          ovc_a = ovf_cnt;
            const float*  al_a  = alpha;    const float* rs_a  = res_scale;
            const float4* x4_a  = (const float4*)x;
            float4*       out_a = (float4*)out;
            float*        outf_a = out;
            int n_a = n, E_a = E, nb_a = nb, EB2_a = EB2, nh_a = nhalf;
            void* args[] = { &row_a, &col_a, &x2_a, &xb_a, &deg_a, &wv_a,
                             &cur_a, &bin_a, &ovf_a, &ovc_a, &al_a, &rs_a,
                             &x4_a, &out_a, &outf_a, &n_a, &E_a, &nb_a,
                             &EB2_a, &nh_a };
            hipError_t err = hipLaunchCooperativeKernel(
                (const void*)k_coop, dim3(nb), dim3(512), args, 0, stream);
            if (err == hipSuccess) return;
            // else fall through
        }
    }

    // ---------- fallback: direct scatter build (round-4 path) ----------
    {
        char* q = (char*)d_ws;
        int*    degf    = (int*)q;            q += (size_t)n * 4;
        int*    ovf_cf  = (int*)q;            q += 4;
        float*  winvf   = (float*)q;          q += (size_t)n * 4;
        int2*   ovff    = (int2*)q;           q += (size_t)OVF_CAP * 8;
        q = align_up(q, 16);
        uint32* xbf     = (uint32*)q;         q += (size_t)n * 128;
        int*    slotsf  = (int*)q;
        const size_t fxd = (size_t)(q - (char*)d_ws);
        int Cf = 0;
        if (ws_size > fxd) {
            size_t c_avail = (ws_size - fxd) / ((size_t)n * 4);
            Cf = (c_avail > 32) ? 32 : (int)c_avail;
        }
        if (Cf < 1) return;
        hipMemsetAsync(degf, 0, (size_t)n * 4 + 4, stream);
        k_prep<<<(E + 255) / 256, 256, 0, stream>>>(
            (const float2*)x, xbf, row, col, degf, slotsf, ovff, ovf_cf,
            nhalf, E, Cf);
        k_winv<<<(n + 255) / 256, 256, 0, stream>>>(degf, winvf, n);
        const long long tt = (long long)n * D_FEAT;
        const int blocks = (int)((tt + 255) / 256);
        k_gather4d<<<blocks, 256, 0, stream>>>(xbf, (const float4*)x, degf, winvf,
                                               slotsf, alpha, res_scale,
                                               (float4*)out, n, Cf);
        k_ovf<<<64, 256, 0, stream>>>(ovff, ovf_cf, x, winvf, alpha, out);
    }
}